// Round 6
// baseline (805.370 us; speedup 1.0000x reference)
//
#include <hip/hip_runtime.h>
#include <hip/hip_bf16.h>

typedef __attribute__((ext_vector_type(8))) short short8;
typedef __attribute__((ext_vector_type(4))) float f32x4;

#define NT 110592   // 48^3 tokens

static __device__ __forceinline__ unsigned int f2bf(float f){
  unsigned int x; __builtin_memcpy(&x,&f,4);
  x += 0x7fffu + ((x>>16)&1u);           // round-to-nearest-even
  return x >> 16;
}

static __device__ __forceinline__ void gll16(const unsigned short* g, unsigned short* l){
  typedef const __attribute__((address_space(1))) unsigned int gu32;
  typedef __attribute__((address_space(3))) unsigned int lu32;
  __builtin_amdgcn_global_load_lds((gu32*)(const void*)g, (lu32*)(void*)l, 16, 0, 0);
}

// ---------- weight convert+transpose: fp32 [R][C] -> bf16 [C][R] ----------
__global__ void tpose(const float* __restrict__ in, unsigned short* __restrict__ out,
                      int R, int Cc){
  int id = blockIdx.x*256 + threadIdx.x;
  if (id < R*Cc){ int r = id / Cc, c = id - r*Cc; out[c*R + r] = (unsigned short)f2bf(in[id]); }
}

// ---------- MFMA GEMM: C[M][N] = A[M][K]*Bt[N][K]^T (+bias) ----------
// R6: BK=32 double-buffered 1-barrier pipeline (T3-min + T14 async-split).
// Per step t: issue A(t+1) loads (fp32->regs if AF32, else gll16) + B(t+1)
// gll16 FIRST; ds_read+MFMA on buf[t&1] (hides load latency); THEN pack+
// ds_write A(t+1) (vmcnt wait lands after MFMA); ONE barrier. 8 steps (K=256).
// LDS 2x(2x4096 short) = 32 KB -> 4 blocks/CU retained (R4 geometry: 512 thr,
// 8 waves 4x2, per-wave 32x64, acc[2][4], VGPR target <=64).
// XOR swizzle invariant: LDS[row][c*8+e] = global[row][(c^((row>>1)&3))*8+e];
// frag read group q^((l16>>1)&3) (verified 0 bank conflicts R1/R4).
// AF32 fuses the fp32->bf16 x-conversion (xconv kernel eliminated).
// 1D grid, XCD-bijective swizzle (m204), bn fastest within XCD chunk.
template<bool CF32, bool AF32>
__global__ __launch_bounds__(512, 8) void gemm_bt(
    const void* __restrict__ Av,             // [M][K] bf16 (AF32=0) or fp32 (AF32=1)
    const unsigned short* __restrict__ Bt,   // [N][K] bf16
    const float* __restrict__ bias,          // [N] fp32 (CF32 only)
    void* __restrict__ Cv,
    int M, int N, int K)
{
  __shared__ __align__(16) unsigned short As[2*4096];  // dbuf x (128 rows x 32 cols)
  __shared__ __align__(16) unsigned short Bs[2*4096];

  // --- XCD-bijective swizzle: consecutive swz land on same XCD ---
  const int nwg = gridDim.x;
  const int bid = blockIdx.x;
  const int qq = nwg >> 3, rr = nwg & 7;
  const int xcd = bid & 7, loc = bid >> 3;
  const int swz = (xcd < rr ? xcd*(qq+1) : rr*(qq+1) + (xcd-rr)*qq) + loc;
  const int nbn = N >> 7;
  const int bn = swz % nbn;           // bn fastest: A-strip L2/L3 reuse
  const int bm = swz / nbn;

  const int tid  = threadIdx.x;       // 0..511
  const int lane = tid & 63;
  const int wave = tid >> 6;          // 0..7
  const int wm = wave >> 1, wn = wave & 1;   // 4x2 wave grid: 32 rows x 64 cols
  const int l16 = lane & 15, q = lane >> 4;

  const int g8  = ((tid&3) ^ ((tid>>3)&3)) * 8;   // swizzled memory col for staging
  const int cg8 = (q ^ ((l16>>1)&3)) * 8;         // swizzled LDS col for frag reads

  const size_t arow0 = (size_t)(bm*128 + (tid>>2))*K;
  const size_t brow0 = (size_t)(bn*128 + (tid>>2))*K;
  const unsigned short* Ab = (const unsigned short*)Av;  // AF32=0 view
  const float*          Af = (const float*)Av;           // AF32=1 view

  f32x4 acc[2][4] = {};
  const int nslab = K >> 5;           // 8

  // ---- prologue: stage slab 0 into buf 0 ----
  if (AF32){
    gll16(Bt + brow0 + g8, &Bs[tid*8]);
    const float* xa = Af + arow0 + g8;
    float4 a0 = *(const float4*)xa, a1 = *(const float4*)(xa+4);
    uint4 p;
    p.x = f2bf(a0.x)|(f2bf(a0.y)<<16); p.y = f2bf(a0.z)|(f2bf(a0.w)<<16);
    p.z = f2bf(a1.x)|(f2bf(a1.y)<<16); p.w = f2bf(a1.z)|(f2bf(a1.w)<<16);
    *(uint4*)&As[tid*8] = p;
  } else {
    gll16(Ab + arow0 + g8, &As[tid*8]);
    gll16(Bt + brow0 + g8, &Bs[tid*8]);
  }
  __syncthreads();

  for (int t = 0; t < nslab; ++t){
    const int cur = t & 1, nxt = cur ^ 1;

    // phase 1: issue next-slab loads (async; latency hides under compute)
    float4 a0, a1;
    if (t + 1 < nslab){
      const int k1 = (t+1) << 5;
      if (AF32){
        const float* xa = Af + arow0 + k1 + g8;
        a0 = *(const float4*)xa; a1 = *(const float4*)(xa+4);
      } else {
        gll16(Ab + arow0 + k1 + g8, &As[nxt*4096 + tid*8]);
      }
      gll16(Bt + brow0 + k1 + g8, &Bs[nxt*4096 + tid*8]);
    }

    // phase 2: compute slab t from buf[cur]
    short8 af[2], bfm[4];
    #pragma unroll
    for (int tt = 0; tt < 2; ++tt)
      af[tt]  = *(const short8*)&As[cur*4096 + (wm*32 + tt*16 + l16)*32 + cg8];
    #pragma unroll
    for (int tt = 0; tt < 4; ++tt)
      bfm[tt] = *(const short8*)&Bs[cur*4096 + (wn*64 + tt*16 + l16)*32 + cg8];
    #pragma unroll
    for (int im = 0; im < 2; ++im)
      #pragma unroll
      for (int in = 0; in < 4; ++in)
        acc[im][in] = __builtin_amdgcn_mfma_f32_16x16x32_bf16(af[im], bfm[in], acc[im][in], 0, 0, 0);

    // phase 3: land next A slab (write-late), single barrier per step
    if (t + 1 < nslab){
      if (AF32){
        uint4 p;
        p.x = f2bf(a0.x)|(f2bf(a0.y)<<16); p.y = f2bf(a0.z)|(f2bf(a0.w)<<16);
        p.z = f2bf(a1.x)|(f2bf(a1.y)<<16); p.w = f2bf(a1.z)|(f2bf(a1.w)<<16);
        *(uint4*)&As[nxt*4096 + tid*8] = p;
      }
      __syncthreads();
    }
  }

  // ---- epilogue ----
  #pragma unroll
  for (int in = 0; in < 4; ++in){
    int col = bn*128 + wn*64 + in*16 + l16;
    float bv = CF32 ? bias[col] : 0.f;
    #pragma unroll
    for (int im = 0; im < 2; ++im){
      int row0 = bm*128 + wm*32 + im*16 + q*4;
      #pragma unroll
      for (int r = 0; r < 4; ++r){
        if (CF32) ((float*)Cv)[(size_t)(row0 + r)*N + col] = acc[im][in][r] + bv;
        else ((unsigned short*)Cv)[(size_t)(row0 + r)*N + col] = (unsigned short)f2bf(acc[im][in][r]);
      }
    }
  }
}

// ---------- MFMA windowed attention, 1 wave per (window,head), no barriers ----
// S^T = K·Q^T via mfma (rows j, cols i); softmax over j = per-lane sum + 2 shfl;
// P -> LDS (bf16) -> B-frags; V^T staged in LDS; O^T = V^T·P^T via mfma.
// Window map (verified R2): scores window (B,C,A), V/out window (A,B,C),
// masks x|B==11, y|C==11, z|A==11; all coords +2 mod 48 (both rolls folded).
__global__ __launch_bounds__(256) void attn3d(
    const unsigned short* __restrict__ qkv,  // [NT][768] bf16: q|k|v
    unsigned short* __restrict__ aout)       // [NT][256] bf16
{
  __shared__ __align__(16) unsigned short sh[4*6912];   // per wave: P[64][72] + VT[32][72]
  const int tid  = threadIdx.x;
  const int wave = tid >> 6, lane = tid & 63;
  const int l16  = lane & 15, q = lane >> 4;
  unsigned short* P  = sh + wave*6912;
  unsigned short* VT = P + 64*72;

  const int wh   = blockIdx.x*4 + wave;
  const int head = wh & 7;
  const int w    = wh >> 3;
  const int A  = w / 144;
  const int B  = (w / 12) % 12;
  const int Cw = w % 12;

  const int iyy = l16 >> 2, izz = l16 & 3;
  int tok_qk[4], tok_v[4];
  #pragma unroll
  for (int t = 0; t < 4; ++t){
    int px = (4*B  + t   + 2) % 48;
    int py = (4*Cw + iyy + 2) % 48;
    int pz = (4*A  + izz + 2) % 48;
    tok_qk[t] = (px*48 + py)*48 + pz;
    int vx = (4*A  + t   + 2) % 48;
    int vy = (4*B  + iyy + 2) % 48;
    int vz = (4*Cw + izz + 2) % 48;
    tok_v[t] = (vx*48 + vy)*48 + vz;
  }

  // stage V^T: lane = token idx, 32 dims -> scalar b16 writes (2-way free)
  {
    int sx = (4*A  + (lane>>4)     + 2) % 48;
    int sy = (4*B  + ((lane>>2)&3) + 2) % 48;
    int sz = (4*Cw + (lane&3)      + 2) % 48;
    const unsigned short* vp = qkv + (size_t)((sx*48+sy)*48+sz)*768 + 512 + head*32;
    uint4 v0 = *(const uint4*)(vp);
    uint4 v1 = *(const uint4*)(vp+8);
    uint4 v2 = *(const uint4*)(vp+16);
    uint4 v3 = *(const uint4*)(vp+24);
    unsigned vv[16] = {v0.x,v0.y,v0.z,v0.w, v1.x,v1.y,v1.z,v1.w,
                       v2.x,v2.y,v2.z,v2.w, v3.x,v3.y,v3.z,v3.w};
    #pragma unroll
    for (int u = 0; u < 16; ++u){
      VT[(2*u+0)*72 + lane] = (unsigned short)(vv[u] & 0xffffu);
      VT[(2*u+1)*72 + lane] = (unsigned short)(vv[u] >> 16);
    }
  }

  // K/Q fragments straight from global (A/B layout: m|n=l16, k=q*8+j)
  short8 kf[4], qf[4];
  #pragma unroll
  for (int t = 0; t < 4; ++t){
    const unsigned short* base = qkv + (size_t)tok_qk[t]*768 + head*32 + q*8;
    qf[t] = *(const short8*)(base);
    kf[t] = *(const short8*)(base + 256);
  }

  f32x4 s[4][4] = {};
  #pragma unroll
  for (int im = 0; im < 4; ++im)
    #pragma unroll
    for (int jn = 0; jn < 4; ++jn)
      s[im][jn] = __builtin_amdgcn_mfma_f32_16x16x32_bf16(kf[im], qf[jn], s[im][jn], 0, 0, 0);

  // scale + mask + exp (no max-sub: |s|<~8), pack P to LDS, row sums
  const float scale = 0.17677669529663687f;
  const int mx = (B == 11), my = (Cw == 11), mz = (A == 11);
  const int dy = my & ((q>>1) ^ (l16>>3));
  float sum4[4] = {0.f,0.f,0.f,0.f};
  #pragma unroll
  for (int jn = 0; jn < 4; ++jn){
    #pragma unroll
    for (int im = 0; im < 4; ++im){
      const int dxy = (mx & ((im>>1) ^ (jn>>1))) | dy;
      float e0 = (dxy | (mz & (0 ^ ((l16>>1)&1)))) ? 0.f : __expf(s[im][jn][0]*scale);
      float e1 = (dxy | (mz & (0 ^ ((l16>>1)&1)))) ? 0.f : __expf(s[im][jn][1]*scale);
      float e2 = (dxy | (mz & (1 ^ ((l16>>1)&1)))) ? 0.f : __expf(s[im][jn][2]*scale);
      float e3 = (dxy | (mz & (1 ^ ((l16>>1)&1)))) ? 0.f : __expf(s[im][jn][3]*scale);
      sum4[jn] += (e0+e1)+(e2+e3);
      uint2 pk;
      pk.x = f2bf(e0) | (f2bf(e1)<<16);
      pk.y = f2bf(e2) | (f2bf(e3)<<16);
      *(uint2*)&P[(jn*16+l16)*72 + im*16 + q*4] = pk;   // row i, cols j..j+3
    }
  }
  #pragma unroll
  for (int jn = 0; jn < 4; ++jn){
    float sj = sum4[jn];
    sj += __shfl_xor(sj, 16);
    sj += __shfl_xor(sj, 32);
    sum4[jn] = 1.f / sj;
  }

  // O^T = V^T · P^T  (M=32 d, N=64 i, K=64 j)
  f32x4 o[2][4] = {};
  #pragma unroll
  for (int ks = 0; ks < 2; ++ks){
    short8 vf[2], pf[4];
    #pragma unroll
    for (int dt = 0; dt < 2; ++dt)
      vf[dt] = *(const short8*)&VT[(dt*16 + l16)*72 + ks*32 + q*8];
    #pragma unroll
    for (int it = 0; it < 4; ++it)
      pf[it] = *(const short8*)&P[(it*16 + l16)*72 + ks*32 + q*8];
    #pragma unroll
    for (int dt = 0; dt < 2; ++dt)
      #pragma unroll
      for (int it = 0; it < 4; ++it)
        o[dt][it] = __builtin_amdgcn_mfma_f32_16x16x32_bf16(vf[dt], pf[it], o[dt][it], 0, 0, 0);
  }

  // epilogue: O^T[d=dt*16+q*4+r][i=it*16+l16] * inv[it] -> aout[tok_v(i)]
  #pragma unroll
  for (int it = 0; it < 4; ++it){
    float inv = sum4[it];
    unsigned short* op = aout + (size_t)tok_v[it]*256 + head*32;
    #pragma unroll
    for (int dt = 0; dt < 2; ++dt){
      uint2 pk;
      pk.x = f2bf(o[dt][it][0]*inv) | (f2bf(o[dt][it][1]*inv) << 16);
      pk.y = f2bf(o[dt][it][2]*inv) | (f2bf(o[dt][it][3]*inv) << 16);
      *(uint2*)(op + dt*16 + q*4) = pk;
    }
  }
}

// ------------------------------- launch ---------------------------------------
extern "C" void kernel_launch(void* const* d_in, const int* in_sizes, int n_in,
                              void* d_out, int out_size, void* d_ws, size_t ws_size,
                              hipStream_t stream) {
  const float* x     = (const float*)d_in[0];  // [NT][256] fp32
  const float* w_qkv = (const float*)d_in[1];  // [256][768] fp32
  const float* w_out = (const float*)d_in[2];  // [256][256] fp32
  const float* b_out = (const float*)d_in[3];  // [256] fp32
  float* out = (float*)d_out;                  // [NT][256] fp32

  unsigned short* qkv   = (unsigned short*)d_ws;                 // NT*768 bf16
  unsigned short* aout  = qkv   + (size_t)NT*768;                // NT*256 bf16
  unsigned short* wqkvT = aout  + (size_t)NT*256;                // 768*256 bf16
  unsigned short* woutT = wqkvT + (size_t)768*256;               // 256*256 bf16

  tpose<<<dim3((256*768 + 255)/256), dim3(256), 0, stream>>>(w_qkv, wqkvT, 256, 768);
  tpose<<<dim3((256*256 + 255)/256), dim3(256), 0, stream>>>(w_out, woutT, 256, 256);

  // gemm1: A = x fp32, converted in-kernel via async-split staging (no xconv).
  gemm_bt<false, true><<<dim3((768/128)*(NT/128)), dim3(512), 0, stream>>>(
      (const void*)x, wqkvT, nullptr, qkv, NT, 768, 256);

  attn3d<<<dim3(13824/4), dim3(256), 0, stream>>>(qkv, aout);

  gemm_bt<true, false><<<dim3((256/128)*(NT/128)), dim3(512), 0, stream>>>(
      (const void*)aout, woutT, b_out, out, NT, 256, 256);
}

// Round 7
// 339.388 us; speedup vs baseline: 2.3730x; 2.3730x over previous
//
#include <hip/hip_runtime.h>
#include <hip/hip_bf16.h>

typedef __attribute__((ext_vector_type(8))) short short8;
typedef __attribute__((ext_vector_type(4))) float f32x4;

#define NT 110592   // 48^3 tokens

static __device__ __forceinline__ unsigned int f2bf(float f){
  unsigned int x; __builtin_memcpy(&x,&f,4);
  x += 0x7fffu + ((x>>16)&1u);           // round-to-nearest-even
  return x >> 16;
}

static __device__ __forceinline__ void gll16(const unsigned short* g, unsigned short* l){
  typedef const __attribute__((address_space(1))) unsigned int gu32;
  typedef __attribute__((address_space(3))) unsigned int lu32;
  __builtin_amdgcn_global_load_lds((gu32*)(const void*)g, (lu32*)(void*)l, 16, 0, 0);
}

// ---------- fused prep: x fp32->bf16 + both weight transposes (1 launch) ----
// blocks [0,13824): xconv 8 elems/thread; [13824,14592): w_qkv T; rest: w_out T.
__global__ void prep(const float* __restrict__ x,      unsigned short* __restrict__ xbf,
                     const float* __restrict__ wqkv,   unsigned short* __restrict__ wqkvT,
                     const float* __restrict__ wout,   unsigned short* __restrict__ woutT){
  const int bid = blockIdx.x;
  if (bid < 13824){
    size_t i = ((size_t)bid*256 + threadIdx.x) * 8;
    float4 a = *(const float4*)(x+i), b = *(const float4*)(x+i+4);
    uint4 pk;
    pk.x = f2bf(a.x)|(f2bf(a.y)<<16); pk.y = f2bf(a.z)|(f2bf(a.w)<<16);
    pk.z = f2bf(b.x)|(f2bf(b.y)<<16); pk.w = f2bf(b.z)|(f2bf(b.w)<<16);
    *(uint4*)(xbf+i) = pk;
  } else if (bid < 14592){
    int id = (bid-13824)*256 + threadIdx.x;           // 196608 = 256*768 exact
    int r = id / 768, c = id - r*768;
    wqkvT[c*256 + r] = (unsigned short)f2bf(wqkv[id]);
  } else {
    int id = (bid-14592)*256 + threadIdx.x;           // 65536 = 256*256 exact
    int r = id >> 8, c = id & 255;
    woutT[c*256 + r] = (unsigned short)f2bf(wout[id]);
  }
}

// ---------- MFMA GEMM: C[M][N] = A[M][K]*Bt[N][K]^T (+bias), bf16 in ----------
// R4-proven structure (79us gemm1): 128x128 tile, BK=64 (two 32-wide halves),
// global_load_lds w16, XOR-swizzled LDS (0 bank conflicts), single-buffer,
// 2 barriers/K-step. 512 threads / 8 waves (4x2), per-wave 32x64, acc[2][4];
// launch_bounds(512,8) -> VGPR 32, occupancy ~59%.
// 1D grid, XCD-bijective swizzle (m204), bn fastest within XCD chunk.
template<bool CF32>
__global__ __launch_bounds__(512, 8) void gemm_bt(
    const unsigned short* __restrict__ A,    // [M][K] bf16
    const unsigned short* __restrict__ Bt,   // [N][K] bf16
    const float* __restrict__ bias,          // [N] fp32 (CF32 only)
    void* __restrict__ Cv,
    int M, int N, int K)
{
  __shared__ __align__(16) unsigned short As[2*4096];  // two 32-wide halves, 16 KB
  __shared__ __align__(16) unsigned short Bs[2*4096];

  // --- XCD-bijective swizzle: consecutive swz land on same XCD ---
  const int nwg = gridDim.x;
  const int bid = blockIdx.x;
  const int qq = nwg >> 3, rr = nwg & 7;
  const int xcd = bid & 7, loc = bid >> 3;
  const int swz = (xcd < rr ? xcd*(qq+1) : rr*(qq+1) + (xcd-rr)*qq) + loc;
  const int nbn = N >> 7;
  const int bn = swz % nbn;           // bn fastest: A-strip L2/L3 reuse
  const int bm = swz / nbn;

  const int tid  = threadIdx.x;       // 0..511
  const int lane = tid & 63;
  const int wave = tid >> 6;          // 0..7
  const int wm = wave >> 1, wn = wave & 1;   // 4x2 wave grid: 32 rows x 64 cols
  const int l16 = lane & 15, q = lane >> 4;

  const size_t arow0 = (size_t)(bm*128 + (tid>>2))*K;   // rows 0..127
  const size_t brow0 = (size_t)(bn*128 + (tid>>2))*K;
  const int g8  = ((tid&3) ^ ((tid>>3)&3)) * 8;   // swizzled memory col for staging
  const int cg8 = (q ^ ((l16>>1)&3)) * 8;         // swizzled LDS col for frag reads

  f32x4 acc[2][4] = {};

  for (int k0 = 0; k0 < K; k0 += 64){
    __syncthreads();
    gll16(A  + arow0 + k0 + g8,       &As[tid*8]);          // half0 (cols k0..k0+31)
    gll16(A  + arow0 + k0 + 32 + g8,  &As[4096 + tid*8]);   // half1
    gll16(Bt + brow0 + k0 + g8,       &Bs[tid*8]);
    gll16(Bt + brow0 + k0 + 32 + g8,  &Bs[4096 + tid*8]);
    __syncthreads();

    #pragma unroll
    for (int h = 0; h < 2; ++h){
      short8 af[2], bfm[4];
      #pragma unroll
      for (int t = 0; t < 2; ++t)
        af[t]  = *(const short8*)&As[h*4096 + (wm*32 + t*16 + l16)*32 + cg8];
      #pragma unroll
      for (int t = 0; t < 4; ++t)
        bfm[t] = *(const short8*)&Bs[h*4096 + (wn*64 + t*16 + l16)*32 + cg8];
      #pragma unroll
      for (int im = 0; im < 2; ++im)
        #pragma unroll
        for (int in = 0; in < 4; ++in)
          acc[im][in] = __builtin_amdgcn_mfma_f32_16x16x32_bf16(af[im], bfm[in], acc[im][in], 0, 0, 0);
    }
  }

  #pragma unroll
  for (int in = 0; in < 4; ++in){
    int col = bn*128 + wn*64 + in*16 + l16;
    float bv = CF32 ? bias[col] : 0.f;
    #pragma unroll
    for (int im = 0; im < 2; ++im){
      int row0 = bm*128 + wm*32 + im*16 + q*4;
      #pragma unroll
      for (int r = 0; r < 4; ++r){
        if (CF32) ((float*)Cv)[(size_t)(row0 + r)*N + col] = acc[im][in][r] + bv;
        else ((unsigned short*)Cv)[(size_t)(row0 + r)*N + col] = (unsigned short)f2bf(acc[im][in][r]);
      }
    }
  }
}

// ---------- MFMA windowed attention, 1 wave per (window,head), no barriers ----
// R7: 2 waves/block (LDS 27.6 KB -> 5 blocks/CU = 10 waves/CU, was 8) and
// s_setprio(1/0) around MFMA clusters (T5 regime: independent waves, m191 +4-7%).
// S^T = K·Q^T via mfma (rows j, cols i); softmax over j = per-lane sum + 2 shfl;
// P -> LDS (bf16) -> B-frags; V^T staged in LDS; O^T = V^T·P^T via mfma.
// Window map (verified R2): scores window (B,C,A), V/out window (A,B,C),
// masks x|B==11, y|C==11, z|A==11; all coords +2 mod 48 (both rolls folded).
__global__ __launch_bounds__(128) void attn3d(
    const unsigned short* __restrict__ qkv,  // [NT][768] bf16: q|k|v
    unsigned short* __restrict__ aout)       // [NT][256] bf16
{
  __shared__ __align__(16) unsigned short sh[2*6912];   // per wave: P[64][72] + VT[32][72]
  const int tid  = threadIdx.x;
  const int wave = tid >> 6, lane = tid & 63;
  const int l16  = lane & 15, q = lane >> 4;
  unsigned short* P  = sh + wave*6912;
  unsigned short* VT = P + 64*72;

  const int wh   = blockIdx.x*2 + wave;
  const int head = wh & 7;
  const int w    = wh >> 3;
  const int A  = w / 144;
  const int B  = (w / 12) % 12;
  const int Cw = w % 12;

  const int iyy = l16 >> 2, izz = l16 & 3;
  int tok_qk[4], tok_v[4];
  #pragma unroll
  for (int t = 0; t < 4; ++t){
    int px = (4*B  + t   + 2) % 48;
    int py = (4*Cw + iyy + 2) % 48;
    int pz = (4*A  + izz + 2) % 48;
    tok_qk[t] = (px*48 + py)*48 + pz;
    int vx = (4*A  + t   + 2) % 48;
    int vy = (4*B  + iyy + 2) % 48;
    int vz = (4*Cw + izz + 2) % 48;
    tok_v[t] = (vx*48 + vy)*48 + vz;
  }

  // stage V^T: lane = token idx, 32 dims -> scalar b16 writes (2-way free)
  {
    int sx = (4*A  + (lane>>4)     + 2) % 48;
    int sy = (4*B  + ((lane>>2)&3) + 2) % 48;
    int sz = (4*Cw + (lane&3)      + 2) % 48;
    const unsigned short* vp = qkv + (size_t)((sx*48+sy)*48+sz)*768 + 512 + head*32;
    uint4 v0 = *(const uint4*)(vp);
    uint4 v1 = *(const uint4*)(vp+8);
    uint4 v2 = *(const uint4*)(vp+16);
    uint4 v3 = *(const uint4*)(vp+24);
    unsigned vv[16] = {v0.x,v0.y,v0.z,v0.w, v1.x,v1.y,v1.z,v1.w,
                       v2.x,v2.y,v2.z,v2.w, v3.x,v3.y,v3.z,v3.w};
    #pragma unroll
    for (int u = 0; u < 16; ++u){
      VT[(2*u+0)*72 + lane] = (unsigned short)(vv[u] & 0xffffu);
      VT[(2*u+1)*72 + lane] = (unsigned short)(vv[u] >> 16);
    }
  }

  // K/Q fragments straight from global (A/B layout: m|n=l16, k=q*8+j)
  short8 kf[4], qf[4];
  #pragma unroll
  for (int t = 0; t < 4; ++t){
    const unsigned short* base = qkv + (size_t)tok_qk[t]*768 + head*32 + q*8;
    qf[t] = *(const short8*)(base);
    kf[t] = *(const short8*)(base + 256);
  }

  f32x4 s[4][4] = {};
  __builtin_amdgcn_s_setprio(1);
  #pragma unroll
  for (int im = 0; im < 4; ++im)
    #pragma unroll
    for (int jn = 0; jn < 4; ++jn)
      s[im][jn] = __builtin_amdgcn_mfma_f32_16x16x32_bf16(kf[im], qf[jn], s[im][jn], 0, 0, 0);
  __builtin_amdgcn_s_setprio(0);

  // scale + mask + exp (no max-sub: |s|<~8), pack P to LDS, row sums
  const float scale = 0.17677669529663687f;
  const int mx = (B == 11), my = (Cw == 11), mz = (A == 11);
  const int dy = my & ((q>>1) ^ (l16>>3));
  float sum4[4] = {0.f,0.f,0.f,0.f};
  #pragma unroll
  for (int jn = 0; jn < 4; ++jn){
    #pragma unroll
    for (int im = 0; im < 4; ++im){
      const int dxy = (mx & ((im>>1) ^ (jn>>1))) | dy;
      float e0 = (dxy | (mz & (0 ^ ((l16>>1)&1)))) ? 0.f : __expf(s[im][jn][0]*scale);
      float e1 = (dxy | (mz & (0 ^ ((l16>>1)&1)))) ? 0.f : __expf(s[im][jn][1]*scale);
      float e2 = (dxy | (mz & (1 ^ ((l16>>1)&1)))) ? 0.f : __expf(s[im][jn][2]*scale);
      float e3 = (dxy | (mz & (1 ^ ((l16>>1)&1)))) ? 0.f : __expf(s[im][jn][3]*scale);
      sum4[jn] += (e0+e1)+(e2+e3);
      uint2 pk;
      pk.x = f2bf(e0) | (f2bf(e1)<<16);
      pk.y = f2bf(e2) | (f2bf(e3)<<16);
      *(uint2*)&P[(jn*16+l16)*72 + im*16 + q*4] = pk;   // row i, cols j..j+3
    }
  }
  #pragma unroll
  for (int jn = 0; jn < 4; ++jn){
    float sj = sum4[jn];
    sj += __shfl_xor(sj, 16);
    sj += __shfl_xor(sj, 32);
    sum4[jn] = 1.f / sj;
  }

  // O^T = V^T · P^T  (M=32 d, N=64 i, K=64 j)
  f32x4 o[2][4] = {};
  __builtin_amdgcn_s_setprio(1);
  #pragma unroll
  for (int ks = 0; ks < 2; ++ks){
    short8 vf[2], pf[4];
    #pragma unroll
    for (int dt = 0; dt < 2; ++dt)
      vf[dt] = *(const short8*)&VT[(dt*16 + l16)*72 + ks*32 + q*8];
    #pragma unroll
    for (int it = 0; it < 4; ++it)
      pf[it] = *(const short8*)&P[(it*16 + l16)*72 + ks*32 + q*8];
    #pragma unroll
    for (int dt = 0; dt < 2; ++dt)
      #pragma unroll
      for (int it = 0; it < 4; ++it)
        o[dt][it] = __builtin_amdgcn_mfma_f32_16x16x32_bf16(vf[dt], pf[it], o[dt][it], 0, 0, 0);
  }
  __builtin_amdgcn_s_setprio(0);

  // epilogue: O^T[d=dt*16+q*4+r][i=it*16+l16] * inv[it] -> aout[tok_v(i)]
  #pragma unroll
  for (int it = 0; it < 4; ++it){
    float inv = sum4[it];
    unsigned short* op = aout + (size_t)tok_v[it]*256 + head*32;
    #pragma unroll
    for (int dt = 0; dt < 2; ++dt){
      uint2 pk;
      pk.x = f2bf(o[dt][it][0]*inv) | (f2bf(o[dt][it][1]*inv) << 16);
      pk.y = f2bf(o[dt][it][2]*inv) | (f2bf(o[dt][it][3]*inv) << 16);
      *(uint2*)(op + dt*16 + q*4) = pk;
    }
  }
}

// ------------------------------- launch ---------------------------------------
extern "C" void kernel_launch(void* const* d_in, const int* in_sizes, int n_in,
                              void* d_out, int out_size, void* d_ws, size_t ws_size,
                              hipStream_t stream) {
  const float* x     = (const float*)d_in[0];  // [NT][256] fp32
  const float* w_qkv = (const float*)d_in[1];  // [256][768] fp32
  const float* w_out = (const float*)d_in[2];  // [256][256] fp32
  const float* b_out = (const float*)d_in[3];  // [256] fp32
  float* out = (float*)d_out;                  // [NT][256] fp32

  unsigned short* qkv   = (unsigned short*)d_ws;                 // NT*768 bf16
  unsigned short* xbf   = qkv   + (size_t)NT*768;                // NT*256 bf16 (aliases aout)
  unsigned short* aout  = xbf;                                   // reused after GEMM1
  unsigned short* wqkvT = xbf   + (size_t)NT*256;                // 768*256 bf16
  unsigned short* woutT = wqkvT + (size_t)768*256;               // 256*256 bf16
  // total ws use ≈ 227 MB

  prep<<<dim3(14848), dim3(256), 0, stream>>>(x, xbf, w_qkv, wqkvT, w_out, woutT);

  // 1D grid + in-kernel XCD-bijective swizzle: A-strip fetched once per XCD
  gemm_bt<false><<<dim3((768/128)*(NT/128)), dim3(512), 0, stream>>>(xbf, wqkvT, nullptr, qkv, NT, 768, 256);

  attn3d<<<dim3(13824/2), dim3(128), 0, stream>>>(qkv, aout);

  gemm_bt<true><<<dim3((256/128)*(NT/128)), dim3(512), 0, stream>>>(aout, woutT, b_out, out, NT, 256, 256);
}